// Round 1
// baseline (406.492 us; speedup 1.0000x reference)
//
#include <hip/hip_runtime.h>

// CapsuleFC: B=64, N=128, A=64, M=128, D=64
// out = [ncv (B*M*D) | na (B*M) | qk (B*N*M)], fp32
constexpr int Bq = 64, Nq = 128, Aq = 64, Mq = 128, Dq = 64;
constexpr int MD = Mq * Dq;    // 8192
constexpr int NM = Nq * Mq;    // 16384
constexpr int NA = Nq * Aq;    // 8192
constexpr int NCV_SZ = Bq * MD;   // 524288
constexpr int NA_SZ  = Bq * Mq;   // 8192
constexpr float SCALE = 0.125f;   // 1/sqrt(64)

// ---------------- init: ncv = 0, na = 1 ----------------
__global__ __launch_bounds__(256) void k0_init(float* __restrict__ out) {
  int i = blockIdx.x * 256 + threadIdx.x;
  if (i < NCV_SZ) out[i] = 0.0f;
  else if (i < NCV_SZ + NA_SZ) out[i] = 1.0f;
}

// ---------------- K1: logits ----------------
// logits[b,n,m] = SCALE * sum_d ( sum_a input[b,n,a]*w[n,a,m,d] ) * ncvin[b,m,d]
// grid (N, M/4), block 256. Per block: C(64b x 256c) = X(64x64) @ W(64x256), c=(ml,d)
__global__ __launch_bounds__(256) void k1_logits(
    const float* __restrict__ input,   // [B,N,A]
    const float* __restrict__ ncvin,   // [B,M,D]
    const float* __restrict__ w,       // [N,A,M,D]
    float* __restrict__ logits) {      // [B,N,M] (qk region of d_out)
  const int n  = blockIdx.x;
  const int m0 = blockIdx.y * 4;
  const int t  = threadIdx.x;
  const int tb = t >> 5;   // 0..7  : b-group (8 b's each)
  const int tc = t & 31;   // 0..31 : col-group (8 cols each)

  __shared__ float Xs[64][68];    // [a][b], padded stride 68 (16B-aligned rows)
  __shared__ float Ws[16][256];   // [k][c]

  float acc[8][8];
#pragma unroll
  for (int i = 0; i < 8; ++i)
#pragma unroll
    for (int j = 0; j < 8; ++j) acc[i][j] = 0.0f;

  // stage X transposed: Xs[a][b] = input[b,n,a]
#pragma unroll
  for (int pass = 0; pass < 4; ++pass) {
    int idx = t * 4 + pass * 1024;     // over 64b x 64a
    int b = idx >> 6, a = idx & 63;
    float4 v = *reinterpret_cast<const float4*>(&input[(size_t)b * NA + (size_t)n * Aq + a]);
    Xs[a + 0][b] = v.x; Xs[a + 1][b] = v.y; Xs[a + 2][b] = v.z; Xs[a + 3][b] = v.w;
  }

  const size_t wb = (size_t)n * (Aq * MD) + (size_t)m0 * Dq;

  for (int kc = 0; kc < 4; ++kc) {
    if (kc) __syncthreads();
    // stage W chunk: Ws[k][c] = w[n, kc*16+k, m0 + c/64, c%64]  (c contiguous in global)
#pragma unroll
    for (int pass = 0; pass < 4; ++pass) {
      int k = (t >> 6) + pass * 4;
      int c = (t & 63) * 4;
      float4 v = *reinterpret_cast<const float4*>(&w[wb + (size_t)(kc * 16 + k) * MD + c]);
      *reinterpret_cast<float4*>(&Ws[k][c]) = v;
    }
    __syncthreads();
#pragma unroll
    for (int k = 0; k < 16; ++k) {
      float xv[8], wv[8];
      *reinterpret_cast<float4*>(&xv[0]) = *reinterpret_cast<const float4*>(&Xs[kc * 16 + k][tb * 8]);
      *reinterpret_cast<float4*>(&xv[4]) = *reinterpret_cast<const float4*>(&Xs[kc * 16 + k][tb * 8 + 4]);
      *reinterpret_cast<float4*>(&wv[0]) = *reinterpret_cast<const float4*>(&Ws[k][tc * 8]);
      *reinterpret_cast<float4*>(&wv[4]) = *reinterpret_cast<const float4*>(&Ws[k][tc * 8 + 4]);
#pragma unroll
      for (int i = 0; i < 8; ++i)
#pragma unroll
        for (int j = 0; j < 8; ++j) acc[i][j] = fmaf(xv[i], wv[j], acc[i][j]);
    }
  }

  // epilogue: fold d-reduction with ncvin, reduce across the 8 threads sharing (tb, ml)
  const int ml = tc >> 3;            // which of the 4 m's
  const int d0 = (tc & 7) * 8;       // 8 d's owned
  const int m  = m0 + ml;
  float lp[8];
#pragma unroll
  for (int i = 0; i < 8; ++i) {
    int b = tb * 8 + i;
    float4 v0 = *reinterpret_cast<const float4*>(&ncvin[(size_t)b * MD + m * Dq + d0]);
    float4 v1 = *reinterpret_cast<const float4*>(&ncvin[(size_t)b * MD + m * Dq + d0 + 4]);
    lp[i] = acc[i][0] * v0.x + acc[i][1] * v0.y + acc[i][2] * v0.z + acc[i][3] * v0.w
          + acc[i][4] * v1.x + acc[i][5] * v1.y + acc[i][6] * v1.z + acc[i][7] * v1.w;
  }
#pragma unroll
  for (int off = 1; off < 8; off <<= 1)
#pragma unroll
    for (int i = 0; i < 8; ++i) lp[i] += __shfl_xor(lp[i], off);
  if ((tc & 7) == 0) {
#pragma unroll
    for (int i = 0; i < 8; ++i) {
      int b = tb * 8 + i;
      logits[(size_t)b * NM + n * Mq + m] = SCALE * lp[i];
    }
  }
}

// ---------------- K2: softmax + act modulation + renorm (in place) ----------------
// one wave per (b,n) row; lane handles m=lane and m=lane+64
__global__ __launch_bounds__(256) void k2_softmax(
    const float* __restrict__ next_act,  // [B,M]
    float* __restrict__ qk) {            // [B,N,M] in/out
  const int row  = blockIdx.x * 4 + (threadIdx.x >> 6);  // b*N + n
  const int lane = threadIdx.x & 63;
  const int b = row >> 7;
  float* p = qk + (size_t)row * Mq;
  float x0 = p[lane], x1 = p[lane + 64];
  float mx = fmaxf(x0, x1);
#pragma unroll
  for (int off = 32; off; off >>= 1) mx = fmaxf(mx, __shfl_xor(mx, off));
  float e0 = __expf(x0 - mx), e1 = __expf(x1 - mx);
  float s = e0 + e1;
#pragma unroll
  for (int off = 32; off; off >>= 1) s += __shfl_xor(s, off);
  float a0 = next_act[b * Mq + lane], a1 = next_act[b * Mq + lane + 64];
  float t0 = (e0 / s) * a0, t1 = (e1 / s) * a1;
  float s2 = t0 + t1;
#pragma unroll
  for (int off = 32; off; off >>= 1) s2 += __shfl_xor(s2, off);
  s2 += 1e-10f;
  p[lane]      = t0 / s2;
  p[lane + 64] = t1 / s2;
}

// ---------------- K3: ncv[b,m,d] = sum_{n,a} (input[b,n,a]*z[b,n,m]) * w[n,a,m,d] ----------------
// z[b,n,m] = qk[b,n,m]*cur_act[b,n]. grid (M/4, N/16), block 256; atomic partials over n-groups.
__global__ __launch_bounds__(256) void k3_aggregate(
    const float* __restrict__ input,     // [B,N,A]
    const float* __restrict__ cur_act,   // [B,N]
    const float* __restrict__ w,         // [N,A,M,D]
    const float* __restrict__ qk,        // [B,N,M] (final)
    float* __restrict__ ncv) {           // [B,M,D], pre-zeroed
  const int m0 = blockIdx.x * 4;
  const int n0 = blockIdx.y * 16;
  const int t  = threadIdx.x;
  const int tb = t >> 5;
  const int tc = t & 31;
  const int ml = tc >> 3;
  const int d0 = (tc & 7) * 8;

  __shared__ float Xs[64][68];
  __shared__ float Ws[16][256];
  __shared__ float Zs[4][64];

  float acc[8][8];
#pragma unroll
  for (int i = 0; i < 8; ++i)
#pragma unroll
    for (int j = 0; j < 8; ++j) acc[i][j] = 0.0f;

  for (int ni = 0; ni < 16; ++ni) {
    const int n = n0 + ni;
    __syncthreads();  // previous iteration's compute done before overwriting Xs/Zs
    // stage X transposed for this n
#pragma unroll
    for (int pass = 0; pass < 4; ++pass) {
      int idx = t * 4 + pass * 1024;
      int b = idx >> 6, a = idx & 63;
      float4 v = *reinterpret_cast<const float4*>(&input[(size_t)b * NA + (size_t)n * Aq + a]);
      Xs[a + 0][b] = v.x; Xs[a + 1][b] = v.y; Xs[a + 2][b] = v.z; Xs[a + 3][b] = v.w;
    }
    // stage Z: Zs[ml][b] = qk[b,n,m0+ml] * cur_act[b,n]
    if (t < 64) {
      float ca = cur_act[t * Nq + n];
      float4 q4 = *reinterpret_cast<const float4*>(&qk[(size_t)t * NM + n * Mq + m0]);
      Zs[0][t] = q4.x * ca; Zs[1][t] = q4.y * ca; Zs[2][t] = q4.z * ca; Zs[3][t] = q4.w * ca;
    }
    const size_t wbn = (size_t)n * (Aq * MD) + (size_t)m0 * Dq;
    for (int kc = 0; kc < 4; ++kc) {
      if (kc) __syncthreads();
#pragma unroll
      for (int pass = 0; pass < 4; ++pass) {
        int k = (t >> 6) + pass * 4;
        int c = (t & 63) * 4;
        float4 v = *reinterpret_cast<const float4*>(&w[wbn + (size_t)(kc * 16 + k) * MD + c]);
        *reinterpret_cast<float4*>(&Ws[k][c]) = v;
      }
      __syncthreads();
      float zr[8];
#pragma unroll
      for (int i = 0; i < 8; ++i) zr[i] = Zs[ml][tb * 8 + i];
#pragma unroll
      for (int k = 0; k < 16; ++k) {
        float xv[8], wv[8];
        *reinterpret_cast<float4*>(&xv[0]) = *reinterpret_cast<const float4*>(&Xs[kc * 16 + k][tb * 8]);
        *reinterpret_cast<float4*>(&xv[4]) = *reinterpret_cast<const float4*>(&Xs[kc * 16 + k][tb * 8 + 4]);
        *reinterpret_cast<float4*>(&wv[0]) = *reinterpret_cast<const float4*>(&Ws[k][tc * 8]);
        *reinterpret_cast<float4*>(&wv[4]) = *reinterpret_cast<const float4*>(&Ws[k][tc * 8 + 4]);
        float xz[8];
#pragma unroll
        for (int i = 0; i < 8; ++i) xz[i] = xv[i] * zr[i];
#pragma unroll
        for (int i = 0; i < 8; ++i)
#pragma unroll
          for (int j = 0; j < 8; ++j) acc[i][j] = fmaf(xz[i], wv[j], acc[i][j]);
      }
    }
  }

  const int m = m0 + ml;
#pragma unroll
  for (int i = 0; i < 8; ++i) {
    int b = tb * 8 + i;
#pragma unroll
    for (int j = 0; j < 8; ++j)
      atomicAdd(&ncv[(size_t)b * MD + m * Dq + d0 + j], acc[i][j]);
  }
}

extern "C" void kernel_launch(void* const* d_in, const int* in_sizes, int n_in,
                              void* d_out, int out_size, void* d_ws, size_t ws_size,
                              hipStream_t stream) {
  const float* input    = (const float*)d_in[0];
  const float* cur_act  = (const float*)d_in[1];
  const float* ncvin    = (const float*)d_in[2];
  const float* next_act = (const float*)d_in[3];
  const float* w        = (const float*)d_in[4];
  // d_in[5] = num_iter (unused by reference)

  float* out = (float*)d_out;
  float* ncv = out;
  float* qk  = out + NCV_SZ + NA_SZ;

  // init ncv=0, na=1
  k0_init<<<(NCV_SZ + NA_SZ + 255) / 256, 256, 0, stream>>>(out);
  // logits into qk region
  k1_logits<<<dim3(Nq, Mq / 4), 256, 0, stream>>>(input, ncvin, w, qk);
  // softmax+renorm in place
  k2_softmax<<<(Bq * Nq) / 4, 256, 0, stream>>>(next_act, qk);
  // aggregation with atomics
  k3_aggregate<<<dim3(Mq / 4, Nq / 16), 256, 0, stream>>>(input, cur_act, w, qk, ncv);
}

// Round 2
// 226.223 us; speedup vs baseline: 1.7969x; 1.7969x over previous
//
#include <hip/hip_runtime.h>

// CapsuleFC: B=64, N=128, A=64, M=128, D=64
// out = [ncv (B*M*D) | na (B*M) | qk (B*N*M)], fp32
typedef __attribute__((ext_vector_type(8))) short bf16x8;
typedef __attribute__((ext_vector_type(4))) float f32x4;
typedef __attribute__((ext_vector_type(4))) unsigned short us4;

constexpr int Bq = 64, Nq = 128, Aq = 64, Mq = 128, Dq = 64;
constexpr int MD = Mq * Dq;    // 8192
constexpr int NM = Nq * Mq;    // 16384
constexpr int NA = Nq * Aq;    // 8192
constexpr int NCV_SZ = Bq * MD;   // 524288
constexpr int NA_SZ  = Bq * Mq;   // 8192
constexpr float SCALE = 0.125f;   // 1/sqrt(64)

__device__ __forceinline__ unsigned short f2b(float f) {  // fp32 -> bf16 RNE
  unsigned u = __float_as_uint(f);
  return (unsigned short)((u + 0x7fffu + ((u >> 16) & 1u)) >> 16);
}
__device__ __forceinline__ float b2f(unsigned short s) {
  return __uint_as_float(((unsigned)s) << 16);
}

// ---- LDS layouts (bf16, XOR-swizzled to break stride-128B bank conflicts) ----
// Xb: [b=64][k=64]  byte(b,k)   = b*128   + ((2k) ^ ((b&7)<<4))              (8 KB)
// Wt: [col=256][k=64] byte(c,k) = c*128   + ((2k) ^ (((c^(c>>2))&7)<<4))     (32 KB)

__device__ __forceinline__ void stageX(char* Xb, const float* __restrict__ input,
                                       int n, int t) {
  const int b = t >> 2, q = t & 3;                 // thread: row b, k in [16q,16q+16)
  const float* src = input + (size_t)b * NA + (size_t)n * Aq + q * 16;
  float4 v0 = ((const float4*)src)[0];
  float4 v1 = ((const float4*)src)[1];
  float4 v2 = ((const float4*)src)[2];
  float4 v3 = ((const float4*)src)[3];
  unsigned short us[16];
  us[0]=f2b(v0.x); us[1]=f2b(v0.y); us[2]=f2b(v0.z); us[3]=f2b(v0.w);
  us[4]=f2b(v1.x); us[5]=f2b(v1.y); us[6]=f2b(v1.z); us[7]=f2b(v1.w);
  us[8]=f2b(v2.x); us[9]=f2b(v2.y); us[10]=f2b(v2.z); us[11]=f2b(v2.w);
  us[12]=f2b(v3.x); us[13]=f2b(v3.y); us[14]=f2b(v3.z); us[15]=f2b(v3.w);
  const int sw = (b & 7) << 4;
  *(bf16x8*)(Xb + b * 128 + ((q * 32) ^ sw))        = *(bf16x8*)&us[0];
  *(bf16x8*)(Xb + b * 128 + (((q * 32) + 16) ^ sw)) = *(bf16x8*)&us[8];
}

__device__ __forceinline__ void stageW(char* Wt, const float* __restrict__ wgt,
                                       size_t wbase, int t) {
  const int wv = t >> 6, l = t & 63;
  const int c0 = l * 4;
#pragma unroll
  for (int sp = 0; sp < 4; ++sp) {
    const int k0 = sp * 16 + wv * 4;               // 4 consecutive k rows
    const float* p = wgt + wbase + (size_t)k0 * MD + c0;
    float4 r0 = *(const float4*)(p);
    float4 r1 = *(const float4*)(p + MD);
    float4 r2 = *(const float4*)(p + 2 * MD);
    float4 r3 = *(const float4*)(p + 3 * MD);
    float c[4][4] = {{r0.x, r1.x, r2.x, r3.x}, {r0.y, r1.y, r2.y, r3.y},
                     {r0.z, r1.z, r2.z, r3.z}, {r0.w, r1.w, r2.w, r3.w}};
#pragma unroll
    for (int cc = 0; cc < 4; ++cc) {               // reg-transpose: 4 k's per col
      const int col = c0 + cc;
      const int swz = ((col ^ (col >> 2)) & 7) << 4;
      us4 u; u[0]=f2b(c[cc][0]); u[1]=f2b(c[cc][1]); u[2]=f2b(c[cc][2]); u[3]=f2b(c[cc][3]);
      *(us4*)(Wt + col * 128 + ((k0 * 2) ^ swz)) = u;
    }
  }
}

// ---------------- init: ncv = 0, na = 1 ----------------
__global__ __launch_bounds__(256) void k0_init(float* __restrict__ out) {
  int i = blockIdx.x * 256 + threadIdx.x;
  if (i < NCV_SZ) out[i] = 0.0f;
  else if (i < NCV_SZ + NA_SZ) out[i] = 1.0f;
}

// ---------------- K1: logits via MFMA ----------------
// grid (N=128, mc=32), block 256 (4 waves; wave wv owns m = mc*4+wv, cols 64wv..64wv+63)
__global__ __launch_bounds__(256) void k1_logits(
    const float* __restrict__ input,   // [B,N,A]
    const float* __restrict__ ncvin,   // [B,M,D]
    const float* __restrict__ wgt,     // [N,A,M,D]
    float* __restrict__ logits) {      // [B,N,M] (qk region)
  const int n  = blockIdx.x;
  const int mc = blockIdx.y;
  const int t  = threadIdx.x;
  const int wv = t >> 6, l = t & 63;
  const int lr = l & 15, g = l >> 4;

  __shared__ uint4 WtL[2048];  // 32 KB
  __shared__ uint4 XbL[512];   // 8 KB
  char* Wt = (char*)WtL;
  char* Xb = (char*)XbL;

  stageX(Xb, input, n, t);
  stageW(Wt, wgt, (size_t)n * Aq * MD + (size_t)mc * 256, t);
  __syncthreads();

  f32x4 acc[4][4];
#pragma unroll
  for (int i = 0; i < 4; ++i)
#pragma unroll
    for (int j = 0; j < 4; ++j) acc[i][j] = (f32x4)(0.0f);

#pragma unroll
  for (int ks = 0; ks < 2; ++ks) {
    const int kbyte = ks * 64 + g * 16;   // 2*(ks*32 + g*8)
    bf16x8 af[4], bfr[4];
#pragma unroll
    for (int i = 0; i < 4; ++i) {
      const int row = 16 * i + lr;
      af[i] = *(const bf16x8*)(Xb + row * 128 + (kbyte ^ ((row & 7) << 4)));
    }
#pragma unroll
    for (int j = 0; j < 4; ++j) {
      const int col = 64 * wv + 16 * j + lr;
      bfr[j] = *(const bf16x8*)(Wt + col * 128 + (kbyte ^ (((col ^ (col >> 2)) & 7) << 4)));
    }
#pragma unroll
    for (int i = 0; i < 4; ++i)
#pragma unroll
      for (int j = 0; j < 4; ++j)
        acc[i][j] = __builtin_amdgcn_mfma_f32_16x16x32_bf16(af[i], bfr[j], acc[i][j], 0, 0, 0);
  }

  // epilogue: logits[b,n,m] = SCALE * sum_d votes[b,d] * ncvin[b,m,d]
  const int m = mc * 4 + wv;
  float lp[4][4];
#pragma unroll
  for (int i = 0; i < 4; ++i)
#pragma unroll
    for (int r = 0; r < 4; ++r) lp[i][r] = 0.0f;
#pragma unroll
  for (int i = 0; i < 4; ++i)
#pragma unroll
    for (int j = 0; j < 4; ++j) {
      const int d = 16 * j + lr;
#pragma unroll
      for (int r = 0; r < 4; ++r) {
        const int b = 16 * i + 4 * g + r;
        lp[i][r] = fmaf(acc[i][j][r], ncvin[(size_t)b * MD + m * Dq + d], lp[i][r]);
      }
    }
#pragma unroll
  for (int off = 1; off < 16; off <<= 1)
#pragma unroll
    for (int i = 0; i < 4; ++i)
#pragma unroll
      for (int r = 0; r < 4; ++r) lp[i][r] += __shfl_xor(lp[i][r], off);
#pragma unroll
  for (int i = 0; i < 4; ++i)
#pragma unroll
    for (int r = 0; r < 4; ++r)
      if (lr == i * 4 + r) {
        const int b = 16 * i + 4 * g + r;
        logits[(size_t)b * NM + (size_t)n * Mq + m] = SCALE * lp[i][r];
      }
}

// ---------------- K2: softmax + act modulation + renorm (in place) ----------------
__global__ __launch_bounds__(256) void k2_softmax(
    const float* __restrict__ next_act,  // [B,M]
    float* __restrict__ qk) {            // [B,N,M] in/out
  const int row  = blockIdx.x * 4 + (threadIdx.x >> 6);  // b*N + n
  const int lane = threadIdx.x & 63;
  const int b = row >> 7;
  float* p = qk + (size_t)row * Mq;
  float x0 = p[lane], x1 = p[lane + 64];
  float mx = fmaxf(x0, x1);
#pragma unroll
  for (int off = 32; off; off >>= 1) mx = fmaxf(mx, __shfl_xor(mx, off));
  float e0 = __expf(x0 - mx), e1 = __expf(x1 - mx);
  float s = e0 + e1;
#pragma unroll
  for (int off = 32; off; off >>= 1) s += __shfl_xor(s, off);
  float a0 = next_act[b * Mq + lane], a1 = next_act[b * Mq + lane + 64];
  float t0 = (e0 / s) * a0, t1 = (e1 / s) * a1;
  float s2 = t0 + t1;
#pragma unroll
  for (int off = 32; off; off >>= 1) s2 += __shfl_xor(s2, off);
  s2 += 1e-10f;
  p[lane]      = t0 / s2;
  p[lane + 64] = t1 / s2;
}

// ---------------- K3: aggregation via MFMA ----------------
// ncv[b,m,d] = sum_{n,a} (input[b,n,a]*qk[b,n,m]*act[b,n]) * w[n,a,m,d]
// grid (mc=32, ns=32), block 256; each block: 4 n's, wave wv owns m = mc*4+wv.
__global__ __launch_bounds__(256) void k3_aggregate(
    const float* __restrict__ input,     // [B,N,A]
    const float* __restrict__ cur_act,   // [B,N]
    const float* __restrict__ wgt,       // [N,A,M,D]
    const float* __restrict__ qk,        // [B,N,M] (final)
    float* __restrict__ ncv) {           // [B,M,D], pre-zeroed
  const int mc = blockIdx.x;
  const int n0 = blockIdx.y * 4;
  const int t  = threadIdx.x;
  const int wv = t >> 6, l = t & 63;
  const int lr = l & 15, g = l >> 4;
  const int m  = mc * 4 + wv;

  __shared__ uint4 WtL[2048];
  __shared__ uint4 XbL[512];
  char* Wt = (char*)WtL;
  char* Xb = (char*)XbL;

  f32x4 acc[4][4];
#pragma unroll
  for (int i = 0; i < 4; ++i)
#pragma unroll
    for (int j = 0; j < 4; ++j) acc[i][j] = (f32x4)(0.0f);

  for (int ni = 0; ni < 4; ++ni) {
    const int n = n0 + ni;
    if (ni) __syncthreads();   // previous iter's MFMA reads done before overwrite
    stageX(Xb, input, n, t);
    stageW(Wt, wgt, (size_t)n * Aq * MD + (size_t)mc * 256, t);
    __syncthreads();

    // per-wave z factors for the 4 A-fragment rows this lane feeds
    float zr[4];
#pragma unroll
    for (int i = 0; i < 4; ++i) {
      const int b = 16 * i + lr;
      zr[i] = qk[(size_t)b * NM + (size_t)n * Mq + m] * cur_act[b * Nq + n];
    }

#pragma unroll
    for (int ks = 0; ks < 2; ++ks) {
      const int kbyte = ks * 64 + g * 16;
      bf16x8 af[4], bfr[4];
#pragma unroll
      for (int i = 0; i < 4; ++i) {
        const int row = 16 * i + lr;
        bf16x8 a = *(const bf16x8*)(Xb + row * 128 + (kbyte ^ ((row & 7) << 4)));
#pragma unroll
        for (int e = 0; e < 8; ++e)
          a[e] = (short)f2b(b2f((unsigned short)a[e]) * zr[i]);
        af[i] = a;
      }
#pragma unroll
      for (int j = 0; j < 4; ++j) {
        const int col = 64 * wv + 16 * j + lr;
        bfr[j] = *(const bf16x8*)(Wt + col * 128 + (kbyte ^ (((col ^ (col >> 2)) & 7) << 4)));
      }
#pragma unroll
      for (int i = 0; i < 4; ++i)
#pragma unroll
        for (int j = 0; j < 4; ++j)
          acc[i][j] = __builtin_amdgcn_mfma_f32_16x16x32_bf16(af[i], bfr[j], acc[i][j], 0, 0, 0);
    }
  }

  // epilogue: atomic partial sums over the 32 n-split blocks
#pragma unroll
  for (int i = 0; i < 4; ++i)
#pragma unroll
    for (int j = 0; j < 4; ++j) {
      const int d = 16 * j + lr;
#pragma unroll
      for (int r = 0; r < 4; ++r) {
        const int b = 16 * i + 4 * g + r;
        atomicAdd(&ncv[(size_t)b * MD + m * Dq + d], acc[i][j][r]);
      }
    }
}

extern "C" void kernel_launch(void* const* d_in, const int* in_sizes, int n_in,
                              void* d_out, int out_size, void* d_ws, size_t ws_size,
                              hipStream_t stream) {
  const float* input    = (const float*)d_in[0];
  const float* cur_act  = (const float*)d_in[1];
  const float* ncvin    = (const float*)d_in[2];
  const float* next_act = (const float*)d_in[3];
  const float* wgt      = (const float*)d_in[4];
  // d_in[5] = num_iter (unused by reference)

  float* out = (float*)d_out;
  float* ncv = out;
  float* qk  = out + NCV_SZ + NA_SZ;

  k0_init<<<(NCV_SZ + NA_SZ + 255) / 256, 256, 0, stream>>>(out);
  k1_logits<<<dim3(Nq, Mq / 4), 256, 0, stream>>>(input, ncvin, wgt, qk);
  k2_softmax<<<(Bq * Nq) / 4, 256, 0, stream>>>(next_act, qk);
  k3_aggregate<<<dim3(Mq / 4, Nq / 4), 256, 0, stream>>>(input, cur_act, wgt, qk, ncv);
}

// Round 3
// 154.576 us; speedup vs baseline: 2.6297x; 1.4635x over previous
//
#include <hip/hip_runtime.h>

// CapsuleFC: B=64, N=128, A=64, M=128, D=64
// out = [ncv (B*M*D) | na (B*M) | qk (B*N*M)], fp32
typedef __attribute__((ext_vector_type(8))) short bf16x8;
typedef __attribute__((ext_vector_type(4))) float f32x4;
typedef __attribute__((ext_vector_type(4))) unsigned short us4;

constexpr int Bq = 64, Nq = 128, Aq = 64, Mq = 128, Dq = 64;
constexpr int MD = Mq * Dq;    // 8192
constexpr int NM = Nq * Mq;    // 16384
constexpr int NA = Nq * Aq;    // 8192
constexpr int NCV_SZ = Bq * MD;   // 524288
constexpr int NA_SZ  = Bq * Mq;   // 8192
constexpr float SCALE = 0.125f;   // 1/sqrt(64)

__device__ __forceinline__ unsigned short f2b(float f) {  // fp32 -> bf16 RNE
  unsigned u = __float_as_uint(f);
  return (unsigned short)((u + 0x7fffu + ((u >> 16) & 1u)) >> 16);
}
__device__ __forceinline__ float b2f(unsigned short s) {
  return __uint_as_float(((unsigned)s) << 16);
}

// ---- LDS layouts (bf16, XOR-swizzled to break stride-128B bank conflicts) ----
// Xb: [b=64][k=64]  byte(b,k)   = b*128   + ((2k) ^ ((b&7)<<4))              (8 KB)
// Wt: [col=256][k=64] byte(c,k) = c*128   + ((2k) ^ (((c^(c>>2))&7)<<4))     (32 KB)

__device__ __forceinline__ void stageX(char* Xb, const float* __restrict__ input,
                                       int n, int t) {
  const int b = t >> 2, q = t & 3;                 // thread: row b, k in [16q,16q+16)
  const float* src = input + (size_t)b * NA + (size_t)n * Aq + q * 16;
  float4 v0 = ((const float4*)src)[0];
  float4 v1 = ((const float4*)src)[1];
  float4 v2 = ((const float4*)src)[2];
  float4 v3 = ((const float4*)src)[3];
  unsigned short us[16];
  us[0]=f2b(v0.x); us[1]=f2b(v0.y); us[2]=f2b(v0.z); us[3]=f2b(v0.w);
  us[4]=f2b(v1.x); us[5]=f2b(v1.y); us[6]=f2b(v1.z); us[7]=f2b(v1.w);
  us[8]=f2b(v2.x); us[9]=f2b(v2.y); us[10]=f2b(v2.z); us[11]=f2b(v2.w);
  us[12]=f2b(v3.x); us[13]=f2b(v3.y); us[14]=f2b(v3.z); us[15]=f2b(v3.w);
  const int sw = (b & 7) << 4;
  *(bf16x8*)(Xb + b * 128 + ((q * 32) ^ sw))        = *(bf16x8*)&us[0];
  *(bf16x8*)(Xb + b * 128 + (((q * 32) + 16) ^ sw)) = *(bf16x8*)&us[8];
}

// NB = loads batched ahead of the first conversion/write (MLP depth).
template<int NB>
__device__ __forceinline__ void stageW(char* Wt, const float* __restrict__ wgt,
                                       size_t wbase, int t) {
  const int wv = t >> 6, l = t & 63;
  const int c0 = l * 4;
  const float* base = wgt + wbase + c0;
#pragma unroll
  for (int h = 0; h < 16 / NB; ++h) {
    float4 r[NB];
#pragma unroll
    for (int u = 0; u < NB; ++u) {                 // issue ALL NB loads first
      const int idx = h * NB + u;
      const int sp = idx >> 2, rr = idx & 3;
      const int k0 = sp * 16 + wv * 4;
      r[u] = *(const float4*)(base + (size_t)(k0 + rr) * MD);
    }
#pragma unroll
    for (int u = 0; u < NB; u += 4) {              // then convert/transpose/write
      const int idx = h * NB + u;
      const int k0 = (idx >> 2) * 16 + wv * 4;
      float4 r0 = r[u], r1 = r[u + 1], r2 = r[u + 2], r3 = r[u + 3];
      float c[4][4] = {{r0.x, r1.x, r2.x, r3.x}, {r0.y, r1.y, r2.y, r3.y},
                       {r0.z, r1.z, r2.z, r3.z}, {r0.w, r1.w, r2.w, r3.w}};
#pragma unroll
      for (int cc = 0; cc < 4; ++cc) {
        const int col = c0 + cc;
        const int swz = ((col ^ (col >> 2)) & 7) << 4;
        us4 uu; uu[0]=f2b(c[cc][0]); uu[1]=f2b(c[cc][1]); uu[2]=f2b(c[cc][2]); uu[3]=f2b(c[cc][3]);
        *(us4*)(Wt + col * 128 + ((k0 * 2) ^ swz)) = uu;
      }
    }
  }
}

// ---------------- init: ncv = 0, na = 1 ----------------
__global__ __launch_bounds__(256) void k0_init(float* __restrict__ out) {
  int i = blockIdx.x * 256 + threadIdx.x;
  if (i < NCV_SZ) out[i] = 0.0f;
  else if (i < NCV_SZ + NA_SZ) out[i] = 1.0f;
}

// ---------------- K1: logits via MFMA ----------------
// grid (mc=32, n=128), block 256 (4 waves; wave wv owns m = mc*4+wv)
__global__ __launch_bounds__(256) void k1_logits(
    const float* __restrict__ input,   // [B,N,A]
    const float* __restrict__ ncvin,   // [B,M,D]
    const float* __restrict__ wgt,     // [N,A,M,D]
    float* __restrict__ logits) {      // [B,N,M] (qk region)
  const int mc = blockIdx.x;
  const int n  = blockIdx.y;
  const int t  = threadIdx.x;
  const int wv = t >> 6, l = t & 63;
  const int lr = l & 15, g = l >> 4;

  __shared__ uint4 WtL[2048];  // 32 KB
  __shared__ uint4 XbL[512];   // 8 KB
  char* Wt = (char*)WtL;
  char* Xb = (char*)XbL;

  stageX(Xb, input, n, t);
  stageW<16>(Wt, wgt, (size_t)n * Aq * MD + (size_t)mc * 256, t);
  __syncthreads();

  f32x4 acc[4][4];
#pragma unroll
  for (int i = 0; i < 4; ++i)
#pragma unroll
    for (int j = 0; j < 4; ++j) acc[i][j] = (f32x4)(0.0f);

#pragma unroll
  for (int ks = 0; ks < 2; ++ks) {
    const int kbyte = ks * 64 + g * 16;   // 2*(ks*32 + g*8)
    bf16x8 af[4], bfr[4];
#pragma unroll
    for (int i = 0; i < 4; ++i) {
      const int row = 16 * i + lr;
      af[i] = *(const bf16x8*)(Xb + row * 128 + (kbyte ^ ((row & 7) << 4)));
    }
#pragma unroll
    for (int j = 0; j < 4; ++j) {
      const int col = 64 * wv + 16 * j + lr;
      bfr[j] = *(const bf16x8*)(Wt + col * 128 + (kbyte ^ (((col ^ (col >> 2)) & 7) << 4)));
    }
#pragma unroll
    for (int i = 0; i < 4; ++i)
#pragma unroll
      for (int j = 0; j < 4; ++j)
        acc[i][j] = __builtin_amdgcn_mfma_f32_16x16x32_bf16(af[i], bfr[j], acc[i][j], 0, 0, 0);
  }

  // epilogue: logits[b,n,m] = SCALE * sum_d votes[b,d] * ncvin[b,m,d]
  const int m = mc * 4 + wv;
  float lp[4][4];
#pragma unroll
  for (int i = 0; i < 4; ++i)
#pragma unroll
    for (int r = 0; r < 4; ++r) lp[i][r] = 0.0f;
#pragma unroll
  for (int i = 0; i < 4; ++i)
#pragma unroll
    for (int j = 0; j < 4; ++j) {
      const int d = 16 * j + lr;
#pragma unroll
      for (int r = 0; r < 4; ++r) {
        const int b = 16 * i + 4 * g + r;
        lp[i][r] = fmaf(acc[i][j][r], ncvin[(size_t)b * MD + m * Dq + d], lp[i][r]);
      }
    }
#pragma unroll
  for (int off = 1; off < 16; off <<= 1)
#pragma unroll
    for (int i = 0; i < 4; ++i)
#pragma unroll
      for (int r = 0; r < 4; ++r) lp[i][r] += __shfl_xor(lp[i][r], off);
#pragma unroll
  for (int i = 0; i < 4; ++i)
#pragma unroll
    for (int r = 0; r < 4; ++r)
      if (lr == i * 4 + r) {
        const int b = 16 * i + 4 * g + r;
        logits[(size_t)b * NM + (size_t)n * Mq + m] = SCALE * lp[i][r];
      }
}

// ---------------- K2: softmax + act modulation + renorm (in place) ----------------
__global__ __launch_bounds__(256) void k2_softmax(
    const float* __restrict__ next_act,  // [B,M]
    float* __restrict__ qk) {            // [B,N,M] in/out
  const int row  = blockIdx.x * 4 + (threadIdx.x >> 6);  // b*N + n
  const int lane = threadIdx.x & 63;
  const int b = row >> 7;
  float* p = qk + (size_t)row * Mq;
  float x0 = p[lane], x1 = p[lane + 64];
  float mx = fmaxf(x0, x1);
#pragma unroll
  for (int off = 32; off; off >>= 1) mx = fmaxf(mx, __shfl_xor(mx, off));
  float e0 = __expf(x0 - mx), e1 = __expf(x1 - mx);
  float s = e0 + e1;
#pragma unroll
  for (int off = 32; off; off >>= 1) s += __shfl_xor(s, off);
  float a0 = next_act[b * Mq + lane], a1 = next_act[b * Mq + lane + 64];
  float t0 = (e0 / s) * a0, t1 = (e1 / s) * a1;
  float s2 = t0 + t1;
#pragma unroll
  for (int off = 32; off; off >>= 1) s2 += __shfl_xor(s2, off);
  s2 += 1e-10f;
  p[lane]      = t0 / s2;
  p[lane + 64] = t1 / s2;
}

// ---------------- K3: aggregation via MFMA ----------------
// ncv[b,m,d] = sum_{n,a} (input[b,n,a]*qk[b,n,m]*act[b,n]) * w[n,a,m,d]
// grid (mc=32, ns=32), block 256; each block: 4 n's, wave wv owns m = mc*4+wv.
__global__ __launch_bounds__(256) void k3_aggregate(
    const float* __restrict__ input,     // [B,N,A]
    const float* __restrict__ cur_act,   // [B,N]
    const float* __restrict__ wgt,       // [N,A,M,D]
    const float* __restrict__ qk,        // [B,N,M] (final)
    float* __restrict__ ncv) {           // [B,M,D], pre-zeroed
  const int mc = blockIdx.x;
  const int n0 = blockIdx.y * 4;
  const int t  = threadIdx.x;
  const int wv = t >> 6, l = t & 63;
  const int lr = l & 15, g = l >> 4;
  const int m  = mc * 4 + wv;

  __shared__ uint4 WtL[2048];
  __shared__ uint4 XbL[512];
  char* Wt = (char*)WtL;
  char* Xb = (char*)XbL;

  f32x4 acc[4][4];
#pragma unroll
  for (int i = 0; i < 4; ++i)
#pragma unroll
    for (int j = 0; j < 4; ++j) acc[i][j] = (f32x4)(0.0f);

  for (int ni = 0; ni < 4; ++ni) {
    const int n = n0 + ni;
    if (ni) __syncthreads();   // previous iter's MFMA reads done before overwrite
    stageX(Xb, input, n, t);
    stageW<8>(Wt, wgt, (size_t)n * Aq * MD + (size_t)mc * 256, t);
    __syncthreads();

    // per-wave z factors for the 4 A-fragment rows this lane feeds
    float zr[4];
#pragma unroll
    for (int i = 0; i < 4; ++i) {
      const int b = 16 * i + lr;
      zr[i] = qk[(size_t)b * NM + (size_t)n * Mq + m] * cur_act[b * Nq + n];
    }

#pragma unroll
    for (int ks = 0; ks < 2; ++ks) {
      const int kbyte = ks * 64 + g * 16;
      bf16x8 af[4], bfr[4];
#pragma unroll
      for (int i = 0; i < 4; ++i) {
        const int row = 16 * i + lr;
        bf16x8 a = *(const bf16x8*)(Xb + row * 128 + (kbyte ^ ((row & 7) << 4)));
#pragma unroll
        for (int e = 0; e < 8; ++e)
          a[e] = (short)f2b(b2f((unsigned short)a[e]) * zr[i]);
        af[i] = a;
      }
#pragma unroll
      for (int j = 0; j < 4; ++j) {
        const int col = 64 * wv + 16 * j + lr;
        bfr[j] = *(const bf16x8*)(Wt + col * 128 + (kbyte ^ (((col ^ (col >> 2)) & 7) << 4)));
      }
#pragma unroll
      for (int i = 0; i < 4; ++i)
#pragma unroll
        for (int j = 0; j < 4; ++j)
          acc[i][j] = __builtin_amdgcn_mfma_f32_16x16x32_bf16(af[i], bfr[j], acc[i][j], 0, 0, 0);
    }
  }

  // epilogue: atomic partial sums over the 32 n-split blocks
#pragma unroll
  for (int i = 0; i < 4; ++i)
#pragma unroll
    for (int j = 0; j < 4; ++j) {
      const int d = 16 * j + lr;
#pragma unroll
      for (int r = 0; r < 4; ++r) {
        const int b = 16 * i + 4 * g + r;
        atomicAdd(&ncv[(size_t)b * MD + m * Dq + d], acc[i][j][r]);
      }
    }
}

extern "C" void kernel_launch(void* const* d_in, const int* in_sizes, int n_in,
                              void* d_out, int out_size, void* d_ws, size_t ws_size,
                              hipStream_t stream) {
  const float* input    = (const float*)d_in[0];
  const float* cur_act  = (const float*)d_in[1];
  const float* ncvin    = (const float*)d_in[2];
  const float* next_act = (const float*)d_in[3];
  const float* wgt      = (const float*)d_in[4];
  // d_in[5] = num_iter (unused by reference)

  float* out = (float*)d_out;
  float* ncv = out;
  float* qk  = out + NCV_SZ + NA_SZ;

  k0_init<<<(NCV_SZ + NA_SZ + 255) / 256, 256, 0, stream>>>(out);
  k1_logits<<<dim3(Mq / 4, Nq), 256, 0, stream>>>(input, ncvin, wgt, qk);
  k2_softmax<<<(Bq * Nq) / 4, 256, 0, stream>>>(next_act, qk);
  k3_aggregate<<<dim3(Mq / 4, Nq / 4), 256, 0, stream>>>(input, cur_act, wgt, qk, ncv);
}